// Round 4
// baseline (872.033 us; speedup 1.0000x reference)
//
#include <hip/hip_runtime.h>

typedef unsigned short u16;
typedef u16   u16x4 __attribute__((ext_vector_type(4)));
typedef u16   u16x8 __attribute__((ext_vector_type(8)));
typedef short s16x8 __attribute__((ext_vector_type(8)));
typedef float f32x4 __attribute__((ext_vector_type(4)));

#define NSEQ 256
#define NRES 384
#define NF   64
#define NP   32
#define NO   128

__device__ __forceinline__ u16 f2b(float f) {
    union { float f; unsigned u; } c; c.f = f;
    unsigned r = c.u + 0x7fffu + ((c.u >> 16) & 1u);   // RNE
    return (u16)(r >> 16);
}

// ---------------------------------------------------------------------------
// Kernel 0: fused {Wo f32->bf16 conversion} + {norm matrix}.
// blocks 0..127: convert; blocks 128..703: norm tiles (24x24 grid flattened).
// ---------------------------------------------------------------------------
__global__ __launch_bounds__(256) void k_prep_norm(
    const float* __restrict__ Wo, u16* __restrict__ WoB,
    const float* __restrict__ mask, float* __restrict__ normMat)
{
    const int t = threadIdx.x;
    if (blockIdx.x < 128) {
        int idx = blockIdx.x * 256 + t;                // [0, 32768)
        f32x4 v = *(const f32x4*)(Wo + idx * 4);
        u16x4 o;
        #pragma unroll
        for (int e = 0; e < 4; ++e) o[e] = f2b(v[e]);
        *(u16x4*)(WoB + idx * 4) = o;
        return;
    }
    __shared__ float mi[256][17], mj[256][17];
    const int bx = blockIdx.x - 128;
    const int iB = (bx / 24) * 16, jB = (bx % 24) * 16;
    #pragma unroll
    for (int it = 0; it < 16; ++it) {
        int ss = it * 16 + (t >> 4);
        int c  = t & 15;
        mi[ss][c] = mask[(long)ss * NRES + iB + c];
        mj[ss][c] = mask[(long)ss * NRES + jB + c];
    }
    __syncthreads();
    const int ti = t >> 4, tj = t & 15;
    float acc = 0.f;
    for (int ss = 0; ss < 256; ++ss) acc += mi[ss][ti] * mj[ss][tj];
    normMat[(long)(iB + ti) * NRES + jB + tj] = acc;
}

// ---------------------------------------------------------------------------
// Kernel 1: LayerNorm + dual projection + mask -> leftT/rightT (bf16) in
// [ic = i*32+p][s] layout. Block 256 = residue i x 64 s. Grid (384, 4).
// Compute mapping keeps Mt reads wave-uniform (broadcast, conflict-free);
// output goes through an LDS transpose so global stores are 128-B contiguous.
// ---------------------------------------------------------------------------
__global__ __launch_bounds__(256) void k_lnproj(
    const float* __restrict__ M, const float* __restrict__ mask,
    const float* __restrict__ gamma, const float* __restrict__ beta,
    const float* __restrict__ Wa, const float* __restrict__ ba,
    const float* __restrict__ Wb, const float* __restrict__ bb,
    u16* __restrict__ leftT, u16* __restrict__ rightT)
{
    __shared__ float Mt[64][68];        // [s][f]
    __shared__ u16   Tr[64][68];        // [lr*32+p][s] output transpose buf
    __shared__ float gs[64], bs[64], bias[64], mk[64];
    const int t  = threadIdx.x;
    const int i  = blockIdx.x;
    const int s0 = blockIdx.y * 64;
    const int s  = t >> 2, f0 = (t & 3) * 16;

    {   // stage M tile: thread -> 16 contiguous f (64 B)
        const float* g = M + ((long)(s0 + s) * NRES + i) * NF + f0;
        #pragma unroll
        for (int q = 0; q < 4; ++q) {
            f32x4 v = *(const f32x4*)(g + q * 4);
            #pragma unroll
            for (int e = 0; e < 4; ++e) Mt[s][f0 + q * 4 + e] = v[e];
        }
    }
    if (t < 64) { gs[t] = gamma[t]; bs[t] = beta[t];
                  mk[t] = mask[(long)(s0 + t) * NRES + i]; }
    if (t < 32) { bias[t] = ba[t]; bias[32 + t] = bb[t]; }
    __syncthreads();

    // LN stats: 4 threads per s, shfl_xor within aligned group-of-4
    float sum = 0.f, sq = 0.f;
    #pragma unroll
    for (int e = 0; e < 16; ++e) { float v = Mt[s][f0 + e]; sum += v; sq += v * v; }
    sum += __shfl_xor(sum, 1); sq += __shfl_xor(sq, 1);
    sum += __shfl_xor(sum, 2); sq += __shfl_xor(sq, 2);
    float mu  = sum * (1.f / 64.f);
    float var = sq * (1.f / 64.f) - mu * mu;
    float rs  = rsqrtf(var + 1e-5f);
    #pragma unroll
    for (int e = 0; e < 16; ++e) {
        int f = f0 + e;
        Mt[s][f] = (Mt[s][f] - mu) * rs * gs[f] + bs[f];
    }
    __syncthreads();

    // projection: sg = wave (uniform), rowid = lane -> (lr, p); W in VGPRs
    const int sg = t >> 6, rowid = t & 63;
    const int lr = rowid >> 5, p = rowid & 31;
    const float* Wg = (lr ? Wb : Wa) + p * 64;
    f32x4 wreg[16];
    #pragma unroll
    for (int q = 0; q < 16; ++q) wreg[q] = *(const f32x4*)(Wg + q * 4);

    float accv[16];
    #pragma unroll
    for (int e = 0; e < 16; ++e) accv[e] = 0.f;
    #pragma unroll 4
    for (int f4 = 0; f4 < 16; ++f4) {
        f32x4 w4 = wreg[f4];
        #pragma unroll
        for (int e = 0; e < 16; ++e) {
            f32x4 m4 = *(const f32x4*)(&Mt[sg * 16 + e][f4 * 4]);  // broadcast
            accv[e] += m4[0]*w4[0] + m4[1]*w4[1] + m4[2]*w4[2] + m4[3]*w4[3];
        }
    }
    const float b_ = bias[rowid];
    #pragma unroll
    for (int e = 0; e < 16; ++e)
        Tr[rowid][sg * 16 + e] = f2b((accv[e] + b_) * mk[sg * 16 + e]);
    __syncthreads();

    // coalesced store: 4 consecutive lanes cover one row's 64 s (128 B)
    const int r = t >> 2, ch = t & 3;
    const int lr2 = r >> 5, p2 = r & 31;
    u16* dst = (lr2 ? rightT : leftT) + ((long)i * NP + p2) * NSEQ + s0 + ch * 16;
    *(u16x8*)dst       = *(const u16x8*)&Tr[r][ch * 16];
    *(u16x8*)(dst + 8) = *(const u16x8*)&Tr[r][ch * 16 + 8];
}

// ---------------------------------------------------------------------------
// Kernel 2: fused outer-product GEMM + Wo projection + epilogue.
// No stage-1 LDS: A/B fragments load DIRECTLY from global (leftT/rightT are
// stored in fragment layout). Zero barriers in the K-loop; single barrier
// total (Os overlay). Zraw/norm/bo prefetched at block start.
// Grid 9216 x 256 (4 waves). LDS = 32 KB Os (xor-swizzled) -> 5 blocks/CU.
// ---------------------------------------------------------------------------
__device__ __forceinline__ void mfma16(f32x4 acc[4][4], const u16x8 af[4],
                                       const u16x8 bf[4]) {
    #pragma unroll
    for (int mt = 0; mt < 4; ++mt)
        #pragma unroll
        for (int nt = 0; nt < 4; ++nt)
            acc[mt][nt] = __builtin_amdgcn_mfma_f32_16x16x32_bf16(
                (s16x8)af[mt], (s16x8)bf[nt], acc[mt][nt], 0, 0, 0);
}
__device__ __forceinline__ void loadAB(const u16* aP, const u16* bP, int k0,
                                       u16x8 af[4], u16x8 bf[4]) {
    #pragma unroll
    for (int mt = 0; mt < 4; ++mt) {
        af[mt] = *(const u16x8*)(aP + mt * 16 * NSEQ + k0);
        bf[mt] = *(const u16x8*)(bP + mt * 16 * NSEQ + k0);
    }
}

__global__ __launch_bounds__(256, 5) void k_main(
    const u16* __restrict__ leftT, const u16* __restrict__ rightT,
    const float* __restrict__ normMat,
    const u16* __restrict__ WoB, const float* __restrict__ bo,
    const float* __restrict__ Zraw, float* __restrict__ out)
{
    __shared__ __align__(16) u16 Os[128 * 128];   // xor-swizzled O tile

    // supertile decode: 8x8 blocks per supertile, 12x12 supertiles
    const int bid = blockIdx.x;
    const int st = bid >> 6, wi = bid & 63;
    const int xT = (st % 12) * 8 + (wi & 7);
    const int yT = (st / 12) * 8 + (wi >> 3);

    const int t    = threadIdx.x;
    const int wave = t >> 6, lane = t & 63;
    const int quad = lane >> 4, l16 = lane & 15;
    const int wr = wave >> 1, wc = wave & 1;
    const long icBase = (long)xT * 128;
    const long jdBase = (long)yT * 128;
    const int  ob = wave * 32;

    // ---- prefetch epilogue operands (independent of everything) ----
    const int i0 = xT * 4, j0 = yT * 4;
    float zr[8], nr[4], bov0, bov1;
    #pragma unroll
    for (int rg = 0; rg < 4; ++rg) {
        int pair = quad * 4 + rg;
        int i = i0 + (pair >> 2), j = j0 + (pair & 3);
        nr[rg] = normMat[(long)i * NRES + j];
        #pragma unroll
        for (int nt = 0; nt < 2; ++nt)
            zr[nt * 4 + rg] = Zraw[((long)i * NRES + j) * NO + ob + nt * 16 + l16];
    }
    bov0 = bo[ob + l16]; bov1 = bo[ob + 16 + l16];

    // ---- stage 1: K-loop, direct-global fragments, no barriers ----
    const u16* aP = leftT  + (icBase + wr * 64 + l16) * NSEQ + quad * 8;
    const u16* bP = rightT + (jdBase + wc * 64 + l16) * NSEQ + quad * 8;

    f32x4 acc[4][4] = {};
    u16x8 afA[4], bfA[4], afB[4], bfB[4];
    loadAB(aP, bP, 0, afA, bfA);
    #pragma unroll
    for (int kt = 0; kt < 8; kt += 2) {
        loadAB(aP, bP, (kt + 1) * 32, afB, bfB);
        mfma16(acc, afA, bfA);
        if (kt + 2 < 8) loadAB(aP, bP, (kt + 2) * 32, afA, bfA);
        mfma16(acc, afB, bfB);
    }

    // ---- O tile -> swizzled LDS (C/D layout: row = quad*4+rg, col = l16) ----
    #pragma unroll
    for (int mt = 0; mt < 4; ++mt)
        #pragma unroll
        for (int nt = 0; nt < 4; ++nt)
            #pragma unroll
            for (int rg = 0; rg < 4; ++rg) {
                int row = wr * 64 + mt * 16 + quad * 4 + rg;
                int col = wc * 64 + nt * 16 + l16;
                int key = (row & 7) ^ ((row >> 5) & 3);
                Os[row * 128 + (((col >> 3) ^ key) << 3) + (col & 7)]
                    = f2b(acc[mt][nt][rg]);
            }
    __syncthreads();   // the only barrier

    // ---- stage 2: Z2[pair][o] = sum_k O_pair[k] * Wo[o][k] ----
    f32x4 acc2[2] = {};
    const int ii = l16 >> 2, jj = l16 & 3;
    const u16* wp0 = WoB + (long)(ob + l16) * 1024 + quad * 8;
    const u16* wp1 = wp0 + 16 * 1024;
    #pragma unroll 8
    for (int kk = 0; kk < 32; ++kk) {
        u16x8 b0 = *(const u16x8*)(wp0 + kk * 32);
        u16x8 b1 = *(const u16x8*)(wp1 + kk * 32);
        int key = (kk & 7) ^ ii;
        u16x8 a2 = *(const u16x8*)&Os[(ii * 32 + kk) * 128
                                      + (((jj * 4 + quad) ^ key) << 3)];
        acc2[0] = __builtin_amdgcn_mfma_f32_16x16x32_bf16((s16x8)a2, (s16x8)b0, acc2[0], 0, 0, 0);
        acc2[1] = __builtin_amdgcn_mfma_f32_16x16x32_bf16((s16x8)a2, (s16x8)b1, acc2[1], 0, 0, 0);
    }

    // ---- epilogue: (z + bo)/(0.001+norm) + Zraw (prefetched) ----
    #pragma unroll
    for (int nt = 0; nt < 2; ++nt) {
        float bv = nt ? bov1 : bov0;
        #pragma unroll
        for (int rg = 0; rg < 4; ++rg) {
            int pair = quad * 4 + rg;
            int i = i0 + (pair >> 2), j = j0 + (pair & 3);
            long off = ((long)i * NRES + j) * NO + ob + nt * 16 + l16;
            out[off] = (acc2[nt][rg] + bv) / (0.001f + nr[rg]) + zr[nt * 4 + rg];
        }
    }
}

extern "C" void kernel_launch(void* const* d_in, const int* in_sizes, int n_in,
                              void* d_out, int out_size, void* d_ws, size_t ws_size,
                              hipStream_t stream)
{
    const float* M     = (const float*)d_in[0];
    const float* mask  = (const float*)d_in[1];
    const float* Zraw  = (const float*)d_in[2];
    const float* gamma = (const float*)d_in[3];
    const float* beta  = (const float*)d_in[4];
    const float* Wa    = (const float*)d_in[5];
    const float* ba    = (const float*)d_in[6];
    const float* Wb    = (const float*)d_in[7];
    const float* bb    = (const float*)d_in[8];
    const float* Wo    = (const float*)d_in[9];
    const float* bo    = (const float*)d_in[10];
    float* out = (float*)d_out;

    char* ws = (char*)d_ws;
    u16*   leftT   = (u16*)ws;                      // 12288 x 256 bf16
    u16*   rightT  = (u16*)(ws + 6291456);
    float* normMat = (float*)(ws + 12582912);       // 384x384 f32
    u16*   WoB     = (u16*)(ws + 13172736);         // 128x1024 bf16

    k_prep_norm<<<dim3(704), dim3(256), 0, stream>>>(Wo, WoB, mask, normMat);
    k_lnproj<<<dim3(NRES, 4), dim3(256), 0, stream>>>(M, mask, gamma, beta,
                                                      Wa, ba, Wb, bb, leftT, rightT);
    k_main<<<dim3(9216), dim3(256), 0, stream>>>(leftT, rightT, normMat,
                                                 WoB, bo, Zraw, out);
}